// Round 7
// baseline (38.827 us; speedup 1.0000x reference)
//
#include <hip/hip_runtime.h>

#define NCOLORS 10
#define EPS 1e-8f
#define HW 4096
#define S_DIM 16
#define THREADS 256
#define WAVES 4
#define K_BLOCK 2048                     // K per block (half of HW)
#define K_PER_WAVE (K_BLOCK / WAVES)     // 512
#define ITERS (K_PER_WAVE / 32)          // 16 MFMAs per wave

typedef __bf16 bf16x8 __attribute__((ext_vector_type(8)));
typedef float  f32x4  __attribute__((ext_vector_type(4)));
typedef float  f32x4v __attribute__((ext_vector_type(4)));
typedef int    i32x4v __attribute__((ext_vector_type(4)));

// Pass 1: block = (b, half). Computes partial 16x10 weighted histogram over
// K range [half*2048, +2048) via MFMA; stores 160 floats to ws[blk].
// No atomics. NT loads: every cache line is touched by exactly one block.
__global__ __launch_bounds__(THREADS, 4)   // 4 blocks/CU = 16 waves/CU
void color_entropy_pass1(const float* __restrict__ attn,   // [B, S, HW]
                         const int* __restrict__ grids,    // [B, HW]
                         float* __restrict__ ws)           // [2B][160]
{
    const int blk  = blockIdx.x;
    const int b    = blk >> 1;
    const int khalf= (blk & 1) * K_BLOCK;
    const int tid  = threadIdx.x;
    const int lane = tid & 63;
    const int wave = tid >> 6;      // 0..3
    const int sc   = lane & 15;     // A-row (s) AND one-hot col (color)
    const int grp  = lane >> 4;     // k sub-group within the 32-wide K tile

    const float* aBase = attn + ((size_t)b * S_DIM + sc) * HW + khalf + grp * 8;
    const int*   gBase = grids + (size_t)b * HW + khalf + grp * 8;

    const __bf16 ONE  = (__bf16)1.0f;
    const __bf16 ZER  = (__bf16)0.0f;

    f32x4 acc = {0.f, 0.f, 0.f, 0.f};

#pragma unroll 2
    for (int it = 0; it < ITERS; ++it) {
        const int k0 = wave * K_PER_WAVE + it * 32;
        const f32x4v f0 = __builtin_nontemporal_load((const f32x4v*)(aBase + k0));
        const f32x4v f1 = __builtin_nontemporal_load((const f32x4v*)(aBase + k0 + 4));
        const i32x4v g0 = __builtin_nontemporal_load((const i32x4v*)(gBase + k0));
        const i32x4v g1 = __builtin_nontemporal_load((const i32x4v*)(gBase + k0 + 4));

        bf16x8 a;
        a[0] = (__bf16)f0.x; a[1] = (__bf16)f0.y;
        a[2] = (__bf16)f0.z; a[3] = (__bf16)f0.w;
        a[4] = (__bf16)f1.x; a[5] = (__bf16)f1.y;
        a[6] = (__bf16)f1.z; a[7] = (__bf16)f1.w;

        bf16x8 oh;
        oh[0] = (g0.x == sc) ? ONE : ZER;
        oh[1] = (g0.y == sc) ? ONE : ZER;
        oh[2] = (g0.z == sc) ? ONE : ZER;
        oh[3] = (g0.w == sc) ? ONE : ZER;
        oh[4] = (g1.x == sc) ? ONE : ZER;
        oh[5] = (g1.y == sc) ? ONE : ZER;
        oh[6] = (g1.z == sc) ? ONE : ZER;
        oh[7] = (g1.w == sc) ? ONE : ZER;

        acc = __builtin_amdgcn_mfma_f32_16x16x32_bf16(a, oh, acc, 0, 0, 0);
    }

    // D layout: D[row = grp*4 + j][col = sc] = acc[j]
    __shared__ float red[WAVES][256];
#pragma unroll
    for (int j = 0; j < 4; ++j)
        red[wave][(grp * 4 + j) * 16 + sc] = acc[j];
    __syncthreads();

    {
        float s = red[0][tid] + red[1][tid] + red[2][tid] + red[3][tid];
        const int srow = tid >> 4;
        const int c    = tid & 15;
        if (c < NCOLORS)
            ws[(size_t)blk * 160 + srow * 10 + c] = s;   // plain store
    }
}

// Pass 2: thread g = (b, s): merge the two K-half histograms, entropy,
// block-reduce, one atomicAdd per block (32 total).
__global__ __launch_bounds__(256)
void color_entropy_pass2(const float* __restrict__ ws, float* __restrict__ out,
                         float inv_BS)
{
    const int g    = blockIdx.x * 256 + threadIdx.x;   // 0..8191
    const int b    = g >> 4;
    const int s    = g & 15;
    const int tid  = threadIdx.x;
    const int lane = tid & 63;
    const int wave = tid >> 6;

    const float* p0 = ws + (size_t)(b * 2 + 0) * 160 + s * 10;
    const float* p1 = ws + (size_t)(b * 2 + 1) * 160 + s * 10;

    float bins[NCOLORS];
    float tot = 0.f;
#pragma unroll
    for (int c = 0; c < NCOLORS; ++c) {
        bins[c] = p0[c] + p1[c];
        tot += bins[c];
    }
    const float inv = 1.0f / (tot + EPS);
    float e = 0.f;
#pragma unroll
    for (int c = 0; c < NCOLORS; ++c) {
        const float p = bins[c] * inv;
        e -= p * __logf(p + EPS);
    }

#pragma unroll
    for (int off = 32; off >= 1; off >>= 1)
        e += __shfl_xor(e, off, 64);

    __shared__ float sred[4];
    if (lane == 0) sred[wave] = e;
    __syncthreads();

    if (tid == 0) {
        float t = sred[0] + sred[1] + sred[2] + sred[3];
        atomicAdd(out, t * inv_BS);
    }
}

extern "C" void kernel_launch(void* const* d_in, const int* in_sizes, int n_in,
                              void* d_out, int out_size, void* d_ws, size_t ws_size,
                              hipStream_t stream) {
    const float* attn  = (const float*)d_in[0];
    const int*   grids = (const int*)d_in[1];
    float*       out   = (float*)d_out;
    float*       ws    = (float*)d_ws;

    const int B = in_sizes[1] / HW;               // 512
    const float inv_BS = 1.0f / (float)(B * S_DIM);

    hipMemsetAsync(out, 0, sizeof(float) * out_size, stream);
    color_entropy_pass1<<<B * 2, THREADS, 0, stream>>>(attn, grids, ws);
    color_entropy_pass2<<<(B * S_DIM) / 256, 256, 0, stream>>>(ws, out, inv_BS);
}

// Round 8
// 31.469 us; speedup vs baseline: 1.2338x; 1.2338x over previous
//
#include <hip/hip_runtime.h>

#define NCOLORS 10
#define EPS 1e-8f
#define HW 4096
#define S_DIM 16
#define WAVES 8
#define THREADS (WAVES * 64)             // 512
#define K_PER_WAVE (HW / WAVES)          // 512
#define ITERS (K_PER_WAVE / 32)          // 16 MFMAs per wave

typedef __bf16 bf16x8 __attribute__((ext_vector_type(8)));
typedef float  f32x4  __attribute__((ext_vector_type(4)));

// Pass 1: per-b weighted color histogram via MFMA + entropy; ONE plain store
// per block. No atomics (R5: same-line atomicAdd ~15 ns serialized).
// No NT loads (R7: NT + split-line fragment access double-fetches lines).
__global__ __launch_bounds__(THREADS, 4)   // VGPR <= 128 -> 2 blocks/CU (512 slots = 1 round)
void color_entropy_pass1(const float* __restrict__ attn,   // [B, S, HW]
                         const int* __restrict__ grids,    // [B, HW]
                         float* __restrict__ ws)           // [B]
{
    const int b    = blockIdx.x;
    const int tid  = threadIdx.x;
    const int lane = tid & 63;
    const int wave = tid >> 6;      // 0..7
    const int sc   = lane & 15;     // A-row (s) AND one-hot col (color)
    const int grp  = lane >> 4;     // k sub-group within the 32-wide K tile

    const float* aBase = attn + ((size_t)b * S_DIM + sc) * HW + grp * 8;
    const int*   gBase = grids + (size_t)b * HW + grp * 8;

    const __bf16 ONE  = (__bf16)1.0f;
    const __bf16 ZER  = (__bf16)0.0f;

    f32x4 acc = {0.f, 0.f, 0.f, 0.f};

#pragma unroll 4
    for (int it = 0; it < ITERS; ++it) {
        const int k0 = wave * K_PER_WAVE + it * 32;
        const float4 f0 = *reinterpret_cast<const float4*>(aBase + k0);
        const float4 f1 = *reinterpret_cast<const float4*>(aBase + k0 + 4);
        const int4   g0 = *reinterpret_cast<const int4*>(gBase + k0);
        const int4   g1 = *reinterpret_cast<const int4*>(gBase + k0 + 4);

        bf16x8 a;
        a[0] = (__bf16)f0.x; a[1] = (__bf16)f0.y;
        a[2] = (__bf16)f0.z; a[3] = (__bf16)f0.w;
        a[4] = (__bf16)f1.x; a[5] = (__bf16)f1.y;
        a[6] = (__bf16)f1.z; a[7] = (__bf16)f1.w;

        bf16x8 oh;
        oh[0] = (g0.x == sc) ? ONE : ZER;
        oh[1] = (g0.y == sc) ? ONE : ZER;
        oh[2] = (g0.z == sc) ? ONE : ZER;
        oh[3] = (g0.w == sc) ? ONE : ZER;
        oh[4] = (g1.x == sc) ? ONE : ZER;
        oh[5] = (g1.y == sc) ? ONE : ZER;
        oh[6] = (g1.z == sc) ? ONE : ZER;
        oh[7] = (g1.w == sc) ? ONE : ZER;

        acc = __builtin_amdgcn_mfma_f32_16x16x32_bf16(a, oh, acc, 0, 0, 0);
    }

    // D layout: D[row = grp*4 + j][col = sc] = acc[j]
    __shared__ float red[WAVES][256];
#pragma unroll
    for (int j = 0; j < 4; ++j)
        red[wave][(grp * 4 + j) * 16 + sc] = acc[j];
    __syncthreads();

    if (tid < 256) {
        float s = 0.f;
#pragma unroll
        for (int w = 0; w < WAVES; ++w) s += red[w][tid];
        red[0][tid] = s;
    }
    __syncthreads();

    __shared__ float ent16[S_DIM];
    if (tid < S_DIM) {
        float bins[NCOLORS];
        float tot = 0.f;
#pragma unroll
        for (int c = 0; c < NCOLORS; ++c) {
            bins[c] = red[0][tid * 16 + c];
            tot += bins[c];
        }
        const float inv = 1.0f / (tot + EPS);
        float e = 0.f;
#pragma unroll
        for (int c = 0; c < NCOLORS; ++c) {
            const float p = bins[c] * inv;
            e -= p * __logf(p + EPS);
        }
        ent16[tid] = e;
    }
    __syncthreads();

    if (tid == 0) {
        float s = 0.f;
#pragma unroll
        for (int i = 0; i < S_DIM; ++i) s += ent16[i];
        ws[b] = s;                      // plain store — no atomic
    }
}

// Pass 2: reduce B per-block sums -> out[0]. One block; plain store
// (overwrites, so no memset dispatch needed).
__global__ __launch_bounds__(512)
void color_entropy_pass2(const float* __restrict__ ws, float* __restrict__ out,
                         int n, float inv_BS)
{
    const int tid  = threadIdx.x;
    const int lane = tid & 63;
    const int wave = tid >> 6;

    float v = 0.f;
    for (int i = tid; i < n; i += 512) v += ws[i];

#pragma unroll
    for (int off = 32; off >= 1; off >>= 1)
        v += __shfl_xor(v, off, 64);

    __shared__ float s[8];
    if (lane == 0) s[wave] = v;
    __syncthreads();

    if (tid == 0) {
        float t = 0.f;
#pragma unroll
        for (int w = 0; w < 8; ++w) t += s[w];
        out[0] = t * inv_BS;
    }
}

extern "C" void kernel_launch(void* const* d_in, const int* in_sizes, int n_in,
                              void* d_out, int out_size, void* d_ws, size_t ws_size,
                              hipStream_t stream) {
    const float* attn  = (const float*)d_in[0];
    const int*   grids = (const int*)d_in[1];
    float*       out   = (float*)d_out;
    float*       ws    = (float*)d_ws;

    const int B = in_sizes[1] / HW;               // 512
    const float inv_BS = 1.0f / (float)(B * S_DIM);

    color_entropy_pass1<<<B, THREADS, 0, stream>>>(attn, grids, ws);
    color_entropy_pass2<<<1, 512, 0, stream>>>(ws, out, B, inv_BS);
}

// Round 9
// 29.464 us; speedup vs baseline: 1.3178x; 1.0681x over previous
//
#include <hip/hip_runtime.h>

#define NCOLORS 10
#define EPS 1e-8f
#define HW 4096
#define S_DIM 16
#define WAVES 8
#define THREADS (WAVES * 64)             // 512
#define K_PER_WAVE (HW / WAVES)          // 512
#define ITERS (K_PER_WAVE / 32)          // 16 MFMAs per wave

typedef __bf16 bf16x8 __attribute__((ext_vector_type(8)));
typedef float  f32x4  __attribute__((ext_vector_type(4)));

// Pass 1: per-b weighted color histogram via MFMA + entropy; ONE plain store
// per block. No atomics (R5: same-line atomicAdd ~15 ns serialized).
// No NT loads (R7: NT + split-line access double-fetches). unroll 2, not 4
// (R8: deeper unroll regressed ~4 us — VGPR/occupancy cost, no latency win).
__global__ __launch_bounds__(THREADS, 4)   // VGPR <= 128 -> 2 blocks/CU
void color_entropy_pass1(const float* __restrict__ attn,   // [B, S, HW]
                         const int* __restrict__ grids,    // [B, HW]
                         float* __restrict__ ws)           // [B]
{
    const int b    = blockIdx.x;
    const int tid  = threadIdx.x;
    const int lane = tid & 63;
    const int wave = tid >> 6;      // 0..7
    const int sc   = lane & 15;     // A-row (s) AND one-hot col (color)
    const int grp  = lane >> 4;     // k sub-group within the 32-wide K tile

    const float* aBase = attn + ((size_t)b * S_DIM + sc) * HW + grp * 8;
    const int*   gBase = grids + (size_t)b * HW + grp * 8;

    const __bf16 ONE  = (__bf16)1.0f;
    const __bf16 ZER  = (__bf16)0.0f;

    f32x4 acc = {0.f, 0.f, 0.f, 0.f};

#pragma unroll 2
    for (int it = 0; it < ITERS; ++it) {
        const int k0 = wave * K_PER_WAVE + it * 32;
        const float4 f0 = *reinterpret_cast<const float4*>(aBase + k0);
        const float4 f1 = *reinterpret_cast<const float4*>(aBase + k0 + 4);
        const int4   g0 = *reinterpret_cast<const int4*>(gBase + k0);
        const int4   g1 = *reinterpret_cast<const int4*>(gBase + k0 + 4);

        bf16x8 a;
        a[0] = (__bf16)f0.x; a[1] = (__bf16)f0.y;
        a[2] = (__bf16)f0.z; a[3] = (__bf16)f0.w;
        a[4] = (__bf16)f1.x; a[5] = (__bf16)f1.y;
        a[6] = (__bf16)f1.z; a[7] = (__bf16)f1.w;

        bf16x8 oh;
        oh[0] = (g0.x == sc) ? ONE : ZER;
        oh[1] = (g0.y == sc) ? ONE : ZER;
        oh[2] = (g0.z == sc) ? ONE : ZER;
        oh[3] = (g0.w == sc) ? ONE : ZER;
        oh[4] = (g1.x == sc) ? ONE : ZER;
        oh[5] = (g1.y == sc) ? ONE : ZER;
        oh[6] = (g1.z == sc) ? ONE : ZER;
        oh[7] = (g1.w == sc) ? ONE : ZER;

        acc = __builtin_amdgcn_mfma_f32_16x16x32_bf16(a, oh, acc, 0, 0, 0);
    }

    // D layout: D[row = grp*4 + j][col = sc] = acc[j]
    __shared__ float red[WAVES][256];
#pragma unroll
    for (int j = 0; j < 4; ++j)
        red[wave][(grp * 4 + j) * 16 + sc] = acc[j];
    __syncthreads();

    if (tid < 256) {
        float s = 0.f;
#pragma unroll
        for (int w = 0; w < WAVES; ++w) s += red[w][tid];
        red[0][tid] = s;
    }
    __syncthreads();

    __shared__ float ent16[S_DIM];
    if (tid < S_DIM) {
        float bins[NCOLORS];
        float tot = 0.f;
#pragma unroll
        for (int c = 0; c < NCOLORS; ++c) {
            bins[c] = red[0][tid * 16 + c];
            tot += bins[c];
        }
        const float inv = 1.0f / (tot + EPS);
        float e = 0.f;
#pragma unroll
        for (int c = 0; c < NCOLORS; ++c) {
            const float p = bins[c] * inv;
            e -= p * __logf(p + EPS);
        }
        ent16[tid] = e;
    }
    __syncthreads();

    if (tid == 0) {
        float s = 0.f;
#pragma unroll
        for (int i = 0; i < S_DIM; ++i) s += ent16[i];
        ws[b] = s;                      // plain store — no atomic
    }
}

// Pass 2: reduce B per-block sums -> out[0]. One block; plain store
// (overwrites, so no memset dispatch needed).
__global__ __launch_bounds__(512)
void color_entropy_pass2(const float* __restrict__ ws, float* __restrict__ out,
                         int n, float inv_BS)
{
    const int tid  = threadIdx.x;
    const int lane = tid & 63;
    const int wave = tid >> 6;

    float v = 0.f;
    for (int i = tid; i < n; i += 512) v += ws[i];

#pragma unroll
    for (int off = 32; off >= 1; off >>= 1)
        v += __shfl_xor(v, off, 64);

    __shared__ float s[8];
    if (lane == 0) s[wave] = v;
    __syncthreads();

    if (tid == 0) {
        float t = 0.f;
#pragma unroll
        for (int w = 0; w < 8; ++w) t += s[w];
        out[0] = t * inv_BS;
    }
}

extern "C" void kernel_launch(void* const* d_in, const int* in_sizes, int n_in,
                              void* d_out, int out_size, void* d_ws, size_t ws_size,
                              hipStream_t stream) {
    const float* attn  = (const float*)d_in[0];
    const int*   grids = (const int*)d_in[1];
    float*       out   = (float*)d_out;
    float*       ws    = (float*)d_ws;

    const int B = in_sizes[1] / HW;               // 512
    const float inv_BS = 1.0f / (float)(B * S_DIM);

    color_entropy_pass1<<<B, THREADS, 0, stream>>>(attn, grids, ws);
    color_entropy_pass2<<<1, 512, 0, stream>>>(ws, out, B, inv_BS);
}